// Round 2
// baseline (76.104 us; speedup 1.0000x reference)
//
#include <hip/hip_runtime.h>

// B=256, IN_F=512, K_INT=75, OUT_F=64
// Workspace: Mt[o][b][76] fp32 (k padded to 76, pad col zeroed) = 64*256*76*4 = 4,980,736 B

__global__ __launch_bounds__(256, 4) void md_gemm(const float* __restrict__ x,
                                                  const float* __restrict__ T,
                                                  float* __restrict__ Mt) {
  const int kc = blockIdx.x;        // 0..74
  const int o0 = blockIdx.y << 5;   // 0 / 32
  const int b0 = blockIdx.z << 7;   // 0 / 128
  const int tid = threadIdx.x;

  __shared__ alignas(16) float xT[64 * 128];  // [f_local][b_local], 32 KB
  __shared__ float4 ts4[64 * 8];              // [f_local][o_quad], 8 KB (32 o)

  const int bq = tid & 31;          // b-quad 0..31 -> 4 b's each
  const int og = tid >> 5;          // o-quad 0..7  -> 4 o's each

  float acc[4][4];                  // [e=b][d=o]
#pragma unroll
  for (int e = 0; e < 4; ++e)
#pragma unroll
    for (int d = 0; d < 4; ++d) acc[e][d] = 0.0f;

  const float4* x4 = reinterpret_cast<const float4*>(x);
  const float4* T4 = reinterpret_cast<const float4*>(T);

  for (int fc = 0; fc < 8; ++fc) {
    const int f0 = fc << 6;
    // stage x^T chunk: 128 b x 64 f. Each thread: 8 contiguous float4 of one row.
    {
      const int r = tid & 127;      // b row
      const int ch = tid >> 7;      // 0..1
#pragma unroll
      for (int q = 0; q < 8; ++q) {
        const int c = (ch << 3) + q;                      // f-quad 0..15
        const float4 v = x4[(b0 + r) * 128 + (f0 >> 2) + c];
        xT[((c << 2) + 0) * 128 + r] = v.x;               // bank = r&31: conflict-free
        xT[((c << 2) + 1) * 128 + r] = v.y;
        xT[((c << 2) + 2) * 128 + r] = v.z;
        xT[((c << 2) + 3) * 128 + r] = v.w;
      }
    }
    // stage T chunk: 64 f x 32 o (fixed kc). Coalesced 128 B per f-row.
#pragma unroll
    for (int h = 0; h < 2; ++h) {
      const int idx = tid + (h << 8);                     // 0..511
      const int ff = idx >> 3, c = idx & 7;
      ts4[(ff << 3) + c] = T4[(f0 + ff) * 1200 + kc * 16 + (o0 >> 2) + c];
    }
    __syncthreads();
#pragma unroll 4
    for (int ff = 0; ff < 64; ++ff) {
      const float4 xa = *reinterpret_cast<const float4*>(&xT[(ff << 7) + (bq << 2)]);
      const float4 tb = ts4[(ff << 3) + og];
      acc[0][0] += xa.x * tb.x; acc[0][1] += xa.x * tb.y; acc[0][2] += xa.x * tb.z; acc[0][3] += xa.x * tb.w;
      acc[1][0] += xa.y * tb.x; acc[1][1] += xa.y * tb.y; acc[1][2] += xa.y * tb.z; acc[1][3] += xa.y * tb.w;
      acc[2][0] += xa.z * tb.x; acc[2][1] += xa.z * tb.y; acc[2][2] += xa.z * tb.z; acc[2][3] += xa.z * tb.w;
      acc[3][0] += xa.w * tb.x; acc[3][1] += xa.w * tb.y; acc[3][2] += xa.w * tb.z; acc[3][3] += xa.w * tb.w;
    }
    __syncthreads();
  }

  // store to Mt[o][b][76]; kc==74 blocks also zero the pad column
#pragma unroll
  for (int d = 0; d < 4; ++d) {
    const int o = o0 + (og << 2) + d;
#pragma unroll
    for (int e = 0; e < 4; ++e) {
      const int b = b0 + (bq << 2) + e;
      float* row = Mt + (o * 256 + b) * 76;
      row[kc] = acc[e][d];
      if (kc == 74) row[75] = 0.0f;
    }
  }
}

// One block per (o, 32-i chunk). All 256 rows of M[:, :, o] staged in LDS (row = 76 floats).
// 256 threads = 16 i-slots (2 i each) x 16 j-groups (16 j each).
__global__ __launch_bounds__(256, 2) void md_pair(const float* __restrict__ Mt,
                                                  float* __restrict__ out) {
  const int o = blockIdx.x;           // 0..63
  const int ibase = blockIdx.y << 5;  // 32 i per block
  const int tid = threadIdx.x;

  __shared__ alignas(16) float smem[256 * 76];  // 77,824 B

  // pure contiguous copy: 4864 float4, coalesced global + conflict-free LDS
  {
    const float4* src4 = reinterpret_cast<const float4*>(Mt + o * (256 * 76));
    float4* dst4 = reinterpret_cast<float4*>(smem);
#pragma unroll
    for (int t = 0; t < 19; ++t) dst4[tid + (t << 8)] = src4[tid + (t << 8)];
  }
  __syncthreads();

  const int io = tid & 15;            // i-slot
  const int jg = tid >> 4;            // 0..15
  const int i1 = ibase + (io << 1);

  const float4* mo4 = reinterpret_cast<const float4*>(smem);
  float4 ra[19], rb[19];
#pragma unroll
  for (int c = 0; c < 19; ++c) {
    ra[c] = mo4[i1 * 19 + c];
    rb[c] = mo4[(i1 + 1) * 19 + c];
  }

  float s1 = 0.0f, s2 = 0.0f;
  for (int jj = 0; jj < 16; ++jj) {
    const int j = (jg << 4) + jj;
    const float4* rj = mo4 + j * 19;
    float a0 = 0.f, a1 = 0.f, a2 = 0.f, a3 = 0.f;
    float b0 = 0.f, b1 = 0.f, b2 = 0.f, b3 = 0.f;
#pragma unroll
    for (int c = 0; c < 19; ++c) {
      const float4 v = rj[c];
      a0 += __builtin_fabsf(v.x - ra[c].x);
      a1 += __builtin_fabsf(v.y - ra[c].y);
      a2 += __builtin_fabsf(v.z - ra[c].z);
      a3 += __builtin_fabsf(v.w - ra[c].w);
      b0 += __builtin_fabsf(v.x - rb[c].x);
      b1 += __builtin_fabsf(v.y - rb[c].y);
      b2 += __builtin_fabsf(v.z - rb[c].z);
      b3 += __builtin_fabsf(v.w - rb[c].w);
    }
    s1 += __expf(-((a0 + a1) + (a2 + a3)));   // j==i gives exp(0)=1, cancels -1
    s2 += __expf(-((b0 + b1) + (b2 + b3)));
  }
  __syncthreads();

  // reduce 16 j-group partials per i (red rows padded to 17 to break bank conflicts)
  float* red = smem;
  red[((io << 1) + 0) * 17 + jg] = s1;
  red[((io << 1) + 1) * 17 + jg] = s2;
  __syncthreads();
  if (tid < 32) {
    float s = 0.0f;
#pragma unroll
    for (int g = 0; g < 16; ++g) s += red[tid * 17 + g];
    out[(ibase + tid) * 64 + o] = s - 1.0f;
  }
}

extern "C" void kernel_launch(void* const* d_in, const int* in_sizes, int n_in,
                              void* d_out, int out_size, void* d_ws, size_t ws_size,
                              hipStream_t stream) {
  const float* x = (const float*)d_in[0];   // [256,512]
  const float* T = (const float*)d_in[1];   // [512,75,64]
  float* out = (float*)d_out;               // [256,64]
  float* Mt = (float*)d_ws;                 // [64][256][76]

  md_gemm<<<dim3(75, 2, 2), 256, 0, stream>>>(x, T, Mt);
  md_pair<<<dim3(64, 8), 256, 0, stream>>>(Mt, out);
}